// Round 1
// baseline (619.074 us; speedup 1.0000x reference)
//
#include <hip/hip_runtime.h>

// Jacobi iteration: u' = (f*H^2 + 0.5*sum_n (kc+kn)*Un) / (2*kc + 0.5*sum_n kn)
// B=8, G=1024, interior N=1022, 16 iterations. fp32 throughout.

namespace {
constexpr int    Gf     = 1024;
constexpr int    Ni     = 1022;               // interior size
constexpr int    SK     = 1024;               // kappa/f row stride
constexpr int    SU     = 1024;               // ws u row stride (aligned, pad cols 1022..1023 = 0)
constexpr size_t IMG_K  = (size_t)Gf * Gf;    // 1048576
constexpr size_t IMG_U  = (size_t)Ni * SU;    // 1046528
constexpr size_t IMG_O  = (size_t)Ni * Ni;    // 1044484
constexpr int    NB     = 8;                  // batch
constexpr int    MAXIT  = 16;
}

__device__ __forceinline__ float frcp(float x) { return __builtin_amdgcn_rcpf(x); }

// FIRST: usrc = pre (stride 1022, no pads/guards -> explicit boundary predication)
// LAST : udst = d_out (stride 1022, scalar stores)
// else : stride-1024 ws buffers with zeroed pad columns + guard element at [-1]
template<bool FIRST, bool LAST>
__global__ __launch_bounds__(256)
void jac_step(const float* __restrict__ usrc, float* __restrict__ udst,
              const float* __restrict__ kap,  const float* __restrict__ fin)
{
    const int j0 = (blockIdx.x * 64 + threadIdx.x) * 4;   // 0..1020, multiple of 4
    const int i  = blockIdx.y * 4 + threadIdx.y;          // row
    const int b  = blockIdx.z;
    if (i >= Ni) return;

    const float* kB = kap + (size_t)b * IMG_K;
    const float* kN = kB + (size_t)i * SK;        // kappa row i   -> north coeff
    const float* kC = kN + SK;                    // row i+1       -> center/W/E
    const float* kS = kC + SK;                    // row i+2       -> south
    const float* fC = fin + (size_t)b * IMG_K + (size_t)(i + 1) * SK;

    // kappa/f vector loads (all verified in-bounds for every (b,i,j0))
    const float4 c0 = *(const float4*)(kC + j0);
    const float4 c1 = *(const float4*)(kC + j0 + 4);
    const float4 n0 = *(const float4*)(kN + j0);
    const float4 s0 = *(const float4*)(kS + j0);
    const float4 q0 = *(const float4*)(fC + j0);
    const bool full = (j0 + 3 < Ni);              // lane 3 valid (false only for j0==1020)
    const float n4 = kN[j0 + 4];                  // always in-bounds
    const float s4 = full ? kS[j0 + 4] : 0.0f;    // row i+2 can be 1023 -> guard
    const float q4 = full ? fC[j0 + 4] : 0.0f;

    // per-lane coefficient views (col j0+1+k for c/n/s/f, j0+k for W, j0+2+k for E)
    const float kc[4] = { c0.y, c0.z, c0.w, c1.x };
    const float kn[4] = { n0.y, n0.z, n0.w, n4   };
    const float ks[4] = { s0.y, s0.z, s0.w, s4   };
    const float fv[4] = { q0.y, q0.z, q0.w, q4   };
    const float kw[4] = { c0.x, c0.y, c0.z, c0.w };
    const float ke[4] = { c0.z, c0.w, c1.x, c1.y };

    float un[4], us[4], uw[4], ue[4];
    if (FIRST) {
        const float* uB = usrc + (size_t)b * IMG_O + (size_t)i * Ni;
        #pragma unroll
        for (int k = 0; k < 4; ++k) {
            const int j = j0 + k;
            if (j < Ni) {
                un[k] = (i > 0)      ? uB[j - Ni] : 0.0f;
                us[k] = (i < Ni - 1) ? uB[j + Ni] : 0.0f;
                uw[k] = (j > 0)      ? uB[j - 1]  : 0.0f;
                ue[k] = (j < Ni - 1) ? uB[j + 1]  : 0.0f;
            } else {
                un[k] = us[k] = uw[k] = ue[k] = 0.0f;
            }
        }
    } else {
        const float* uB = usrc + (size_t)b * IMG_U + (size_t)i * SU;
        const float4 z4  = make_float4(0.f, 0.f, 0.f, 0.f);
        const float4 uc0 = *(const float4*)(uB + j0);
        const float4 vn  = (i > 0)      ? *(const float4*)(uB - SU + j0) : z4;  // wave-uniform branch
        const float4 vs  = (i < Ni - 1) ? *(const float4*)(uB + SU + j0) : z4;
        const float uwm = uB[j0 - 1];   // pad col / guard elem -> 0 at boundaries
        const float ue4 = uB[j0 + 4];   // pad col at j0==1018? no: only used when lane3 valid
        un[0] = vn.x;  un[1] = vn.y;  un[2] = vn.z;  un[3] = vn.w;
        us[0] = vs.x;  us[1] = vs.y;  us[2] = vs.z;  us[3] = vs.w;
        uw[0] = uwm;   uw[1] = uc0.x; uw[2] = uc0.y; uw[3] = uc0.z;
        ue[0] = uc0.y; ue[1] = uc0.z; ue[2] = uc0.w; ue[3] = ue4;
    }

    constexpr float H2 = (float)((1.0 / 1023.0) * (1.0 / 1023.0));
    float res[4];
    #pragma unroll
    for (int k = 0; k < 4; ++k) {
        const float s  = (kc[k] + kn[k]) * un[k] + (kc[k] + ks[k]) * us[k]
                       + (kc[k] + kw[k]) * uw[k] + (kc[k] + ke[k]) * ue[k];
        const float y3 = 2.0f * kc[k] + 0.5f * (kn[k] + ks[k] + kw[k] + ke[k]);
        res[k] = fmaf(fv[k], H2, 0.5f * s) * frcp(y3);
    }

    if (LAST) {
        float* oB = udst + (size_t)b * IMG_O + (size_t)i * Ni;
        #pragma unroll
        for (int k = 0; k < 4; ++k) {
            const int j = j0 + k;
            if (j < Ni) oB[j] = res[k];
        }
    } else {
        if (!full) { res[2] = 0.0f; res[3] = 0.0f; }   // maintain zero pad cols 1022..1023
        float* dB = udst + (size_t)b * IMG_U + (size_t)i * SU + j0;
        *(float4*)dB = make_float4(res[0], res[1], res[2], res[3]);
        if (b == 0 && i == 0 && j0 == 0) udst[-1] = 0.0f;   // guard elem for next iter's (0,0) W-read
    }
}

extern "C" void kernel_launch(void* const* d_in, const int* in_sizes, int n_in,
                              void* d_out, int out_size, void* d_ws, size_t ws_size,
                              hipStream_t stream)
{
    const float* pre = (const float*)d_in[0];
    const float* f   = (const float*)d_in[1];
    const float* kap = (const float*)d_in[2];
    float* out = (float*)d_out;

    const size_t BUF = (size_t)NB * IMG_U;      // 8,372,224 floats per u buffer
    float* ws0 = (float*)d_ws + 2048;           // leading guard region (>= one row)
    float* ws1 = ws0 + BUF + 2048;

    dim3 blk(64, 4, 1);
    dim3 grd(4, 256, NB);                       // 4*256*8 = 8192 blocks

    // iter 0: pre -> ws0
    jac_step<true, false><<<grd, blk, 0, stream>>>(pre, ws0, kap, f);
    // iters 1..14: ping-pong
    float* src = ws0; float* dst = ws1;
    for (int t = 1; t < MAXIT - 1; ++t) {
        jac_step<false, false><<<grd, blk, 0, stream>>>(src, dst, kap, f);
        float* tmp = src; src = dst; dst = tmp;
    }
    // iter 15: -> d_out
    jac_step<false, true><<<grd, blk, 0, stream>>>(src, out, kap, f);
}

// Round 2
// 415.462 us; speedup vs baseline: 1.4901x; 1.4901x over previous
//
#include <hip/hip_runtime.h>

// Fused-8 Jacobi: u' = Fn + wN*uN + wS*uS + wW*uW + wE*uE, weights iteration-
// invariant (precomputed per thread into registers). 2 launches x 8 fused
// iterations, u ping-pong in LDS, 48x48 output tile from 64x64 input tile.

namespace {
constexpr int    G    = 1024, Ni = 1022;
constexpr int    TIN  = 64, TOUT = 48, HALO = 8, TSTEPS = 8;
constexpr int    US   = 68;                   // u LDS row stride (floats)
constexpr int    KS   = 66;                   // kappa LDS tile dim/stride
constexpr int    UBUF = TIN * US;             // 4352 floats per u buffer
constexpr size_t IMG_K = (size_t)G * G;
constexpr size_t IMG_P = (size_t)Ni * Ni;     // pre / out image
constexpr size_t WS_STRIDE = 1024;
constexpr size_t IMG_W = (size_t)Ni * WS_STRIDE;
constexpr float  H2 = (float)(1.0 / (1023.0 * 1023.0));
}

__device__ __forceinline__ float frcp(float x) { return __builtin_amdgcn_rcpf(x); }

template<bool FIRST, bool LAST>
__global__ __launch_bounds__(256, 3)
void jac_fused8(const float* __restrict__ usrc, float* __restrict__ udst,
                const float* __restrict__ kap,  const float* __restrict__ fin)
{
    __shared__ float lds[2 * UBUF + KS * KS];   // 52,240 B -> 3 blocks/CU
    float* uA = lds;
    float* uB = lds + UBUF;
    float* kT = lds + 2 * UBUF;

    const int tid = threadIdx.x;
    const int bx = blockIdx.x, by = blockIdx.y, b = blockIdx.z;
    const int X0 = bx * TOUT - HALO;            // global interior col of local 0
    const int Y0 = by * TOUT - HALO;

    const float* kB = kap + (size_t)b * IMG_K;
    const float* fB = fin + (size_t)b * IMG_K;

    // ---- fill u tile (uA), clipped to domain (outside = 0) ----
    if (FIRST) {
        const float* uS = usrc + (size_t)b * IMG_P;   // pre, stride 1022
        for (int lin = tid; lin < TIN * TIN; lin += 256) {
            int r = lin >> 6, c = lin & 63;
            int gy = Y0 + r, gx = X0 + c;
            float v = 0.0f;
            if ((unsigned)gy < (unsigned)Ni && (unsigned)gx < (unsigned)Ni)
                v = uS[(size_t)gy * Ni + gx];
            uA[r * US + c] = v;
        }
    } else {
        const float* uS = usrc + (size_t)b * IMG_W;   // ws, stride 1024 (aligned)
        for (int lin = tid; lin < TIN * TIN / 4; lin += 256) {
            int r = lin >> 4, vc = lin & 15;
            int gy = Y0 + r, gx = X0 + 4 * vc;
            float4 v = make_float4(0.f, 0.f, 0.f, 0.f);
            if ((unsigned)gy < (unsigned)Ni) {
                if (gx >= 0 && gx + 3 < Ni) {
                    v = *(const float4*)(uS + (size_t)gy * WS_STRIDE + gx);
                } else {
                    float t[4];
                    #pragma unroll
                    for (int k = 0; k < 4; ++k) {
                        int g = gx + k;
                        t[k] = ((unsigned)g < (unsigned)Ni) ? uS[(size_t)gy * WS_STRIDE + g] : 0.0f;
                    }
                    v = make_float4(t[0], t[1], t[2], t[3]);
                }
            }
            *(float4*)(uA + r * US + 4 * vc) = v;
        }
    }

    // ---- stage kappa tile: grid rows/cols [Y0, Y0+66) x [X0, X0+66), clipped ----
    for (int lin = tid; lin < KS * KS; lin += 256) {
        int r = lin / KS, c = lin - r * KS;
        int gy = Y0 + r, gx = X0 + c;               // kappa GRID coords
        float v = 0.0f;
        if ((unsigned)gy < (unsigned)G && (unsigned)gx < (unsigned)G)
            v = kB[(size_t)gy * G + gx];
        kT[lin] = v;
    }

    __syncthreads();

    // ---- per-thread fixed 4x4 patch; precompute iteration-invariant weights ----
    const int pr = tid >> 4, pc = tid & 15;
    const int R0 = 4 * pr, C0 = 4 * pc;

    float k6[6][6];
    #pragma unroll
    for (int i = 0; i < 6; ++i)
        #pragma unroll
        for (int j = 0; j < 6; ++j)
            k6[i][j] = kT[(R0 + i) * KS + (C0 + j)];

    float wN[4][4], wS[4][4], wW[4][4], wE[4][4], Fn[4][4];
    #pragma unroll
    for (int dr = 0; dr < 4; ++dr) {
        #pragma unroll
        for (int dc = 0; dc < 4; ++dc) {
            float kc = k6[dr + 1][dc + 1];
            float kn = k6[dr + 0][dc + 1];
            float ks = k6[dr + 2][dc + 1];
            float kw = k6[dr + 1][dc + 0];
            float ke = k6[dr + 1][dc + 2];
            float y3 = 2.0f * kc + 0.5f * (kn + ks + kw + ke);
            float inv = frcp(y3);                // garbage/Inf only at never-valid pts
            wN[dr][dc] = 0.5f * (kc + kn) * inv;
            wS[dr][dc] = 0.5f * (kc + ks) * inv;
            wW[dr][dc] = 0.5f * (kc + kw) * inv;
            wE[dr][dc] = 0.5f * (kc + ke) * inv;
            int gy = Y0 + R0 + dr + 1, gx = X0 + C0 + dc + 1;   // f GRID coords
            float fv = 0.0f;
            if ((unsigned)gy < (unsigned)G && (unsigned)gx < (unsigned)G)
                fv = fB[(size_t)gy * G + gx];
            Fn[dr][dc] = fv * H2 * inv;
        }
    }

    // valid region at iter t (local coords): [max(t,rA), min(64-t,rB)) etc.
    const int rA = -Y0, rB = Ni - Y0;
    const int cA = -X0, cB = Ni - X0;

    auto step = [&](const float* src, float* dst, int t) {
        const int rlo = max(t, rA), rhi = min(TIN - t, rB);
        const int clo = max(t, cA), chi = min(TIN - t, cB);
        float4 u6[6];
        #pragma unroll
        for (int k = 0; k < 6; ++k) {
            int rr = R0 - 1 + k; rr = rr < 0 ? 0 : (rr > TIN - 1 ? TIN - 1 : rr);
            u6[k] = *(const float4*)(src + rr * US + C0);
        }
        float wv[4], ev[4];
        const int cw = C0 > 0 ? C0 - 1 : 0;
        #pragma unroll
        for (int d = 0; d < 4; ++d) {
            wv[d] = src[(R0 + d) * US + cw];
            ev[d] = src[(R0 + d) * US + C0 + 4];   // col<=64 < stride 68, in-bounds
        }
        #pragma unroll
        for (int dr = 0; dr < 4; ++dr) {
            const bool rv = (R0 + dr >= rlo) && (R0 + dr < rhi);
            const float* nn = (const float*)&u6[dr];
            const float* cc = (const float*)&u6[dr + 1];
            const float* ss = (const float*)&u6[dr + 2];
            float res[4];
            #pragma unroll
            for (int dc = 0; dc < 4; ++dc) {
                float uw = (dc == 0) ? wv[dr] : cc[dc - 1];
                float ue = (dc == 3) ? ev[dr] : cc[dc + 1];
                float v = fmaf(wN[dr][dc], nn[dc], Fn[dr][dc]);
                v = fmaf(wS[dr][dc], ss[dc], v);
                v = fmaf(wW[dr][dc], uw, v);
                v = fmaf(wE[dr][dc], ue, v);
                bool valid = rv && (C0 + dc >= clo) && (C0 + dc < chi);
                res[dc] = valid ? v : cc[dc];      // invalid: keep old (OOD stays 0)
            }
            *(float4*)(dst + (R0 + dr) * US + C0) = make_float4(res[0], res[1], res[2], res[3]);
        }
    };

    #pragma unroll
    for (int t = 1; t <= TSTEPS; t += 2) {
        step(uA, uB, t);
        __syncthreads();
        step(uB, uA, t + 1);
        __syncthreads();
    }
    // result (u_8 relative to this kernel) now in uA, valid on [8,56)^2 local

    // ---- coalesced store of the 48x48 output tile ----
    if (LAST) {
        float* oB = udst + (size_t)b * IMG_P;
        for (int lin = tid; lin < TOUT * TOUT; lin += 256) {
            int r = lin / TOUT, c = lin - r * TOUT;
            int gy = by * TOUT + r, gx = bx * TOUT + c;
            if (gy < Ni && gx < Ni)
                oB[(size_t)gy * Ni + gx] = uA[(HALO + r) * US + (HALO + c)];
        }
    } else {
        float* oB = udst + (size_t)b * IMG_W;
        for (int lin = tid; lin < TOUT * TOUT; lin += 256) {
            int r = lin / TOUT, c = lin - r * TOUT;
            int gy = by * TOUT + r, gx = bx * TOUT + c;
            if (gy < Ni && gx < Ni)
                oB[(size_t)gy * WS_STRIDE + gx] = uA[(HALO + r) * US + (HALO + c)];
        }
    }
}

extern "C" void kernel_launch(void* const* d_in, const int* in_sizes, int n_in,
                              void* d_out, int out_size, void* d_ws, size_t ws_size,
                              hipStream_t stream)
{
    const float* pre = (const float*)d_in[0];
    const float* f   = (const float*)d_in[1];
    const float* kap = (const float*)d_in[2];
    float* out = (float*)d_out;
    float* ws  = (float*)d_ws;                 // 8 * 1022 * 1024 floats = 33.5 MB

    dim3 blk(256, 1, 1);
    dim3 grd((Ni + TOUT - 1) / TOUT, (Ni + TOUT - 1) / TOUT, 8);  // 22 x 22 x 8

    jac_fused8<true,  false><<<grd, blk, 0, stream>>>(pre, ws,  kap, f);
    jac_fused8<false, true ><<<grd, blk, 0, stream>>>(ws,  out, kap, f);
}